// Round 13
// baseline (338.996 us; speedup 1.0000x reference)
//
#include <hip/hip_runtime.h>

#define B_ 256
#define L_ 50
#define D_ 128
#define T_ 4
#define NH 8
#define NV 4
#define TB_ (T_*B_)
#define EPSF 1e-5f

typedef _Float16 h8 __attribute__((ext_vector_type(8)));
typedef float f4 __attribute__((ext_vector_type(4)));

__device__ __forceinline__ float waveSum(float v) {
    #pragma unroll
    for (int o = 32; o > 0; o >>= 1) v += __shfl_down(v, o, 64);
    return v;
}

// element offset of scale i inside y buffer: 1024*8*sum_{i'<i}(50-i')
__device__ __forceinline__ size_t yoff(int i) {
    return (size_t)8192 * (size_t)(50 * i - (i * (i - 1)) / 2);
}

// K0: split conv_h_w fp32 -> fp16 (hi | lo*1024), [i][dk][c=16][d] with
// 16B-granule pre-swizzle (granule gd stored at gd^c); zero-pad dk>i, i>=50.
__global__ __launch_bounds__(256) void k0_wsplit(
        const float* __restrict__ w, _Float16* __restrict__ whl) {
    int dk = blockIdx.x, i = blockIdx.y;
    int t = threadIdx.x;
    int c = t >> 4, gd = t & 15;
    int h = c & 7;
    bool live = (i < 50) && (dk <= i);
    const float* src = w + (((size_t)i * NH + h) * L_ + dk) * D_ + gd * 8;
    h8 o;
    #pragma unroll
    for (int e = 0; e < 8; ++e) {
        float wv = live ? src[e] : 0.f;
        _Float16 hi = (_Float16)wv;
        o[e] = (c < 8) ? hi : (_Float16)((wv - (float)hi) * 1024.f);
    }
    *(h8*)(whl + (((size_t)i * 50 + dk) * 16 + c) * 128 + ((gd ^ c) & 15) * 8) = o;
}

// K1: embedding + LayerNorm + LIF(T=4) -> s16 [T*B][L][D] fp16 PRE-SWIZZLED, smean fp32
__global__ __launch_bounds__(128) void k1_embed_ln_lif(
        const int* __restrict__ item, const float* __restrict__ tab,
        const float* __restrict__ g, const float* __restrict__ be,
        _Float16* __restrict__ s16, float* __restrict__ smean) {
    int bid = blockIdx.x;
    int b = bid / L_, l = bid % L_;
    int d = threadIdx.x;
    int wid = d >> 6, lane = d & 63;
    __shared__ float red[2];
    int it = item[b * L_ + l];
    float e = tab[(size_t)it * D_ + d];
    float sm_ = waveSum(e);
    if (lane == 0) red[wid] = sm_;
    __syncthreads();
    float mu = (red[0] + red[1]) * (1.f / 128.f);
    __syncthreads();
    float df = e - mu;
    float s2 = waveSum(df * df);
    if (lane == 0) red[wid] = s2;
    __syncthreads();
    float var = (red[0] + red[1]) * (1.f / 128.f);
    float x = df / sqrtf(var + EPSF) * g[d] + be[d];
    float v = 0.f, acc = 0.f;
    int pos = (((d >> 3) ^ l) & 15) * 8 + (d & 7);   // pre-swizzled slot
    #pragma unroll
    for (int t = 0; t < T_; ++t) {
        v += (x - v) * 0.5f;
        float sp = (v >= 1.f) ? 1.f : 0.f;
        v *= (1.f - sp);
        s16[((size_t)(t * B_ + b) * L_ + l) * D_ + pos] = (_Float16)sp;
        acc += sp;
    }
    smean[((size_t)b * L_ + l) * D_ + d] = acc * 0.25f;
}

// ---- K2u (round-6 verbatim): unified scale-group conv. 512 threads = 8 waves,
// 8 tb/block. Wave = (tb-pair p, dc-half dh). LDS: A 102400 + B slot 16KB.
template<int MTG>
__global__ __launch_bounds__(512, 2) void k2u(
        const _Float16* __restrict__ s16, const _Float16* __restrict__ whl,
        float* __restrict__ y, int gbase) {
    extern __shared__ __align__(16) char lds[];
    char* Bslot = lds + 102400;
    const int NM = 2 * MTG;
    const int tbo = blockIdx.x;              // 8 tb per block
    const int grp = gbase + blockIdx.y;
    const int i0 = grp * 4;
    const int kmax = i0 + 4;
    const int tid = threadIdx.x;
    const int wave = tid >> 6, lane = tid & 63;
    const int p = wave >> 1;                 // tb-pair 0..3
    const int dh = wave & 1;                 // dc half 0/1
    const int c_ = lane & 15, g = lane >> 4;

    // stage A (linear copy; swizzle baked into s16)
    {
        const float4* src = (const float4*)(s16 + (size_t)tbo * 8 * (L_ * D_));
        float4* dst = (float4*)lds;
        for (int idx = tid; idx < 6400; idx += 512) dst[idx] = src[idx];
    }
    // B thread slots: bytes [o0,o0+16) and [o1,o1+16) of the 16KB dk-chunk
    const char* bsrc = (const char*)whl + (size_t)i0 * 50 * 4096;
    const int o0 = tid * 16, o1 = 8192 + tid * 16;
    const int sc0 = o0 >> 12, r0 = o0 & 4095;
    const int sc1 = o1 >> 12, r1 = o1 & 4095;
    const char* g0p = bsrc + (size_t)sc0 * (50 * 4096) + r0;
    const char* g1p = bsrc + (size_t)sc1 * (50 * 4096) + r1;

    float4 n0 = *(const float4*)(g0p);
    float4 n1 = *(const float4*)(g1p);
    __syncthreads();                      // A visible
    *(float4*)(Bslot + o0) = n0;
    *(float4*)(Bslot + o1) = n1;
    __syncthreads();

    f4 acc[4][NM];
    #pragma unroll
    for (int sc = 0; sc < 4; ++sc)
        #pragma unroll
        for (int m = 0; m < NM; ++m) { f4 z = {0.f, 0.f, 0.f, 0.f}; acc[sc][m] = z; }

    for (int dk = 0; dk < kmax; ++dk) {
        const bool more = (dk + 1 < kmax);
        float4 m0, m1;
        if (more) {
            m0 = *(const float4*)(g0p + (size_t)(dk + 1) * 4096);
            m1 = *(const float4*)(g1p + (size_t)(dk + 1) * 4096);
        }
        __builtin_amdgcn_sched_barrier(0);   // keep loads issued before consume
        #pragma unroll
        for (int dci = 0; dci < 2; ++dci) {
            const int dc = dh * 2 + dci;
            h8 bf[4];
            #pragma unroll
            for (int sc = 0; sc < 4; ++sc)
                bf[sc] = *(const h8*)(Bslot + sc * 4096 + c_ * 256 +
                                      ((((dc << 2) + g) ^ c_) & 15) * 16);
            #pragma unroll
            for (int m = 0; m < NM; ++m) {
                const int tbL = p * 2 + (m >= MTG ? 1 : 0);
                const int jt = (m >= MTG) ? m - MTG : m;
                int l = jt * 16 + c_ + dk; if (l > 49) l = 49;
                h8 a = *(const h8*)(lds + tbL * 12800 + l * 256 +
                                    ((((dc << 2) + g) ^ l) & 15) * 16);
                #pragma unroll
                for (int sc = 0; sc < 4; ++sc)
                    acc[sc][m] = __builtin_amdgcn_mfma_f32_16x16x32_f16(a, bf[sc], acc[sc][m], 0, 0, 0);
            }
        }
        __syncthreads();
        if (more) {
            *(float4*)(Bslot + o0) = m0;
            *(float4*)(Bslot + o1) = m1;
        }
        __syncthreads();
    }

    // merge dc-halves: dh=1 writes, dh=0 adds. Padded stride vs bank aliasing.
    const int STR = 2 * NM * 4 + 4;          // floats
    float* mbuf = (float*)lds;               // reuse A region
    #pragma unroll
    for (int half = 0; half < 2; ++half) {
        __syncthreads();
        if (dh == 1) {
            float* wp = mbuf + (size_t)(p * 64 + lane) * STR;
            #pragma unroll
            for (int sc = 0; sc < 2; ++sc)
                #pragma unroll
                for (int m = 0; m < NM; ++m)
                    *(f4*)(wp + (sc * NM + m) * 4) = acc[2 * half + sc][m];
        }
        __syncthreads();
        if (dh == 0) {
            const float* rp = mbuf + (size_t)(p * 64 + lane) * STR;
            #pragma unroll
            for (int sc = 0; sc < 2; ++sc)
                #pragma unroll
                for (int m = 0; m < NM; ++m)
                    acc[2 * half + sc][m] += *(const f4*)(rp + (sc * NM + m) * 4);
        }
    }

    if (dh == 0) {
        const bool hiLane = (c_ < 8);
        const int h = c_ & 7;
        #pragma unroll
        for (int sc = 0; sc < 4; ++sc) {
            const int i = i0 + sc;
            const int J = 50 - i;
            #pragma unroll
            for (int m = 0; m < NM; ++m) {
                const int tbL = p * 2 + (m >= MTG ? 1 : 0);
                const int jt = (m >= MTG) ? m - MTG : m;
                const int tb = tbo * 8 + tbL;
                size_t yb = yoff(i) + ((size_t)tb * NH + h) * J;
                #pragma unroll
                for (int r = 0; r < 4; ++r) {
                    float lo = __shfl_xor(acc[sc][m][r], 8, 64);
                    int j = jt * 16 + g * 4 + r;
                    if (hiLane && j < J) y[yb + j] = acc[sc][m][r] + lo * (1.f / 1024.f);
                }
            }
        }
    }
}

// ---- K2t (round-6 verbatim): tail scales (i>=36), wave box (4 tb, 4 sc, 1 dc).
__global__ __launch_bounds__(512, 2) void k2t(
        const _Float16* __restrict__ s16, const _Float16* __restrict__ whl,
        float* __restrict__ y) {
    extern __shared__ __align__(16) char lds[];
    char* Bslot = lds + 102400;
    const int tbo = blockIdx.x;              // 8 tb per block
    const int i0 = 36 + blockIdx.y * 4;      // 36,40,44,48 (scales 50,51 zero-padded)
    const int kmax = (i0 + 4 <= 50) ? (i0 + 4) : 50;
    const int tid = threadIdx.x;
    const int wave = tid >> 6, lane = tid & 63;
    const int tq = wave >> 2;                // tb-quad 0/1
    const int dc = wave & 3;                 // dc slice 0..3
    const int c_ = lane & 15, g = lane >> 4;

    {
        const float4* src = (const float4*)(s16 + (size_t)tbo * 8 * (L_ * D_));
        float4* dst = (float4*)lds;
        for (int idx = tid; idx < 6400; idx += 512) dst[idx] = src[idx];
    }
    const char* bsrc = (const char*)whl + (size_t)i0 * 204800;
    const int o0 = tid * 16, o1 = 8192 + tid * 16;
    const char* g0p = bsrc + (size_t)(o0 >> 12) * 204800 + (o0 & 4095);
    const char* g1p = bsrc + (size_t)(o1 >> 12) * 204800 + (o1 & 4095);
    float4 n0 = *(const float4*)(g0p);
    float4 n1 = *(const float4*)(g1p);
    __syncthreads();
    *(float4*)(Bslot + o0) = n0;
    *(float4*)(Bslot + o1) = n1;
    __syncthreads();

    f4 acc[4][4];                            // [sc][tt]
    #pragma unroll
    for (int sc = 0; sc < 4; ++sc)
        #pragma unroll
        for (int tt = 0; tt < 4; ++tt) { f4 z = {0.f, 0.f, 0.f, 0.f}; acc[sc][tt] = z; }

    const int boffc = c_ * 256 + ((((dc << 2) + g) ^ c_) & 15) * 16;
    for (int dk = 0; dk < kmax; ++dk) {
        const bool more = (dk + 1 < kmax);
        float4 m0, m1;
        if (more) {
            m0 = *(const float4*)(g0p + (size_t)(dk + 1) * 4096);
            m1 = *(const float4*)(g1p + (size_t)(dk + 1) * 4096);
        }
        __builtin_amdgcn_sched_barrier(0);
        h8 bf[4];
        #pragma unroll
        for (int sc = 0; sc < 4; ++sc)
            bf[sc] = *(const h8*)(Bslot + sc * 4096 + boffc);
        int l = c_ + dk; if (l > 49) l = 49;  // fires only where w==0
        const int aoff = l * 256 + ((((dc << 2) + g) ^ l) & 15) * 16;
        #pragma unroll
        for (int tt = 0; tt < 4; ++tt) {
            h8 a = *(const h8*)(lds + (tq * 4 + tt) * 12800 + aoff);
            #pragma unroll
            for (int sc = 0; sc < 4; ++sc)
                acc[sc][tt] = __builtin_amdgcn_mfma_f32_16x16x32_f16(a, bf[sc], acc[sc][tt], 0, 0, 0);
        }
        __syncthreads();
        if (more) {
            *(float4*)(Bslot + o0) = m0;
            *(float4*)(Bslot + o1) = m1;
        }
        __syncthreads();
    }

    // merge K-partials across dc=1..3 into dc=0 (A region dead now).
    f4* mbuf = (f4*)lds;
    if (dc != 0) {
        f4* wp = mbuf + (size_t)(((dc - 1) * 2 + tq) * 16) * 64 + lane;
        #pragma unroll
        for (int sc = 0; sc < 4; ++sc)
            #pragma unroll
            for (int tt = 0; tt < 4; ++tt)
                wp[(sc * 4 + tt) * 64] = acc[sc][tt];
    }
    __syncthreads();
    if (dc == 0) {
        #pragma unroll
        for (int dd = 0; dd < 3; ++dd) {
            const f4* rp = mbuf + (size_t)((dd * 2 + tq) * 16) * 64 + lane;
            #pragma unroll
            for (int sc = 0; sc < 4; ++sc)
                #pragma unroll
                for (int tt = 0; tt < 4; ++tt)
                    acc[sc][tt] += rp[(sc * 4 + tt) * 64];
        }
        const bool hiLane = (c_ < 8);
        const int h = c_ & 7;
        #pragma unroll
        for (int sc = 0; sc < 4; ++sc) {
            const int i = i0 + sc;
            const int J = 50 - i;
            if (J <= 0) continue;
            #pragma unroll
            for (int tt = 0; tt < 4; ++tt) {
                const int tb = tbo * 8 + tq * 4 + tt;
                size_t yb = yoff(i) + ((size_t)tb * NH + h) * J;
                #pragma unroll
                for (int r = 0; r < 4; ++r) {
                    float lo = __shfl_xor(acc[sc][tt][r], 8, 64);
                    int j = g * 4 + r;
                    if (hiLane && j < J) y[yb + j] = acc[sc][tt][r] + lo * (1.f / 1024.f);
                }
            }
        }
    }
}

// K3: BN stats, two stage (partial over 128-tb chunks, then final)
__global__ __launch_bounds__(256) void k3_partial(
        const float* __restrict__ y, float* __restrict__ psum) {
    int ih = blockIdx.x, ck = blockIdx.y;
    int i = ih >> 3, h = ih & 7;
    int J = 50 - i;
    size_t yb = yoff(i);
    int tid = threadIdx.x;
    int grp = tid >> 5, sub = tid & 31;
    float sm = 0.f, ss = 0.f;
    for (int tb = ck * 128 + grp; tb < (ck + 1) * 128; tb += 8) {
        const float* row = y + yb + ((size_t)tb * NH + h) * J;
        for (int j = sub; j < J; j += 32) { float v = row[j]; sm += v; ss += v * v; }
    }
    __shared__ float r1[4], r2[4];
    float a = waveSum(sm), b = waveSum(ss);
    int wid = tid >> 6, lane = tid & 63;
    if (lane == 0) { r1[wid] = a; r2[wid] = b; }
    __syncthreads();
    if (tid == 0) {
        psum[((size_t)ih * 8 + ck) * 2]     = r1[0] + r1[1] + r1[2] + r1[3];
        psum[((size_t)ih * 8 + ck) * 2 + 1] = r2[0] + r2[1] + r2[2] + r2[3];
    }
}

__global__ __launch_bounds__(256) void k3_final(
        const float* __restrict__ psum, const float* __restrict__ bng,
        float* __restrict__ statm, float* __restrict__ stats_) {
    int ih = blockIdx.x * 256 + threadIdx.x;
    if (ih >= 400) return;
    float S = 0.f, Q = 0.f;
    for (int ck = 0; ck < 8; ++ck) {
        S += psum[((size_t)ih * 8 + ck) * 2];
        Q += psum[((size_t)ih * 8 + ck) * 2 + 1];
    }
    int i = ih >> 3;
    float cnt = 1024.f * (float)(50 - i);
    float m = S / cnt;
    float var = Q / cnt - m * m; if (var < 0.f) var = 0.f;
    statm[ih] = m;
    stats_[ih] = bng[ih] / sqrtf(var + EPSF);
}

// K4: BN + LIF over t + max-pool over j -> poolsum [B,400]
__global__ __launch_bounds__(512) void k4_bn_lif_pool(
        const float* __restrict__ y, const float* __restrict__ statm,
        const float* __restrict__ stats_, const float* __restrict__ bnb,
        float* __restrict__ ps) {
    int b = blockIdx.x, i = blockIdx.y, J = L_ - i;
    int h = threadIdx.x >> 6, lane = threadIdx.x & 63;
    int ih = i * NH + h;
    float m = statm[ih], sc = stats_[ih], bb = bnb[ih];
    size_t yb = yoff(i);
    bool valid = lane < J;
    float v = 0.f; int cnt = 0;
    #pragma unroll
    for (int t = 0; t < T_; ++t) {
        int tb = t * B_ + b;
        float yn;
        if (valid) {
            float raw = y[yb + ((size_t)tb * NH + h) * J + lane];
            yn = (raw - m) * sc + bb;
        } else yn = -1e30f;
        v += (yn - v) * 0.5f;
        bool sp = (v >= 1.f);
        if (sp) v = 0.f;
        if (__any(sp)) cnt++;
    }
    if (lane == 0) ps[(size_t)b * 400 + ih] = (float)cnt;
}

// K_vm: vm[b][c*128+d] = sum_l convv[c][l] * smean[b][l][d]
__global__ __launch_bounds__(128) void k_vm(
        const float* __restrict__ smean, const float* __restrict__ convv,
        float* __restrict__ vm) {
    __shared__ float sm_l[L_ * D_];   // 25.6KB
    int b = blockIdx.x, tid = threadIdx.x;
    for (int idx = tid; idx < L_ * D_; idx += 128)
        sm_l[idx] = smean[(size_t)b * (L_ * D_) + idx];
    __syncthreads();
    int d = tid;
    #pragma unroll
    for (int c = 0; c < NV; ++c) {
        float a = 0.f;
        for (int l = 0; l < L_; ++l) a += convv[c * L_ + l] * sm_l[l * D_ + d];
        vm[((size_t)b * NV + c) * D_ + d] = a;
    }
}

// K5b: final heads, 16-batch-blocked so weights stream once per 16 MACs.
// out[b][d] = fchb[d]+fcvb[d] + sum_ih fchw[d][ih]*(ps[b][ih]*0.25)
//                             + sum_cd fcvw[d][cd]*vm[b][cd]
#define NB5 16
__global__ __launch_bounds__(128) void k5b(
        const float* __restrict__ vm, const float* __restrict__ ps,
        const float* __restrict__ fchw, const float* __restrict__ fchb,
        const float* __restrict__ fcvw, const float* __restrict__ fcvb,
        float* __restrict__ out) {
    __shared__ float ps_l[NB5][400];   // 25.6KB
    __shared__ float vm_l[NB5][512];   // 32.8KB
    int bq = blockIdx.x, tid = threadIdx.x;
    for (int idx = tid; idx < NB5 * 400; idx += 128) {
        int bb = idx / 400, ih = idx - bb * 400;
        ps_l[bb][ih] = ps[(size_t)(bq * NB5 + bb) * 400 + ih] * 0.25f;
    }
    for (int idx = tid; idx < NB5 * 512; idx += 128) {
        int bb = idx >> 9, cd = idx & 511;
        vm_l[bb][cd] = vm[(size_t)(bq * NB5 + bb) * 512 + cd];
    }
    __syncthreads();
    int d = tid;
    float acc[NB5];
    #pragma unroll
    for (int bb = 0; bb < NB5; ++bb) acc[bb] = 0.f;
    const float* wh = fchw + (size_t)d * 400;
    for (int ih = 0; ih < 400; ++ih) {
        float wv = wh[ih];               // L1-resident row, broadcast ps from LDS
        #pragma unroll
        for (int bb = 0; bb < NB5; ++bb) acc[bb] += wv * ps_l[bb][ih];
    }
    const float* wv_ = fcvw + (size_t)d * 512;
    for (int cd = 0; cd < 512; ++cd) {
        float w2 = wv_[cd];
        #pragma unroll
        for (int bb = 0; bb < NB5; ++bb) acc[bb] += w2 * vm_l[bb][cd];
    }
    float bias = fchb[d] + fcvb[d];
    #pragma unroll
    for (int bb = 0; bb < NB5; ++bb)
        out[(size_t)(bq * NB5 + bb) * D_ + d] = acc[bb] + bias;
}

extern "C" void kernel_launch(void* const* d_in, const int* in_sizes, int n_in,
                              void* d_out, int out_size, void* d_ws, size_t ws_size,
                              hipStream_t stream) {
    const int*   item  = (const int*)d_in[0];
    const float* tab   = (const float*)d_in[1];
    const float* lng   = (const float*)d_in[2];
    const float* lnb   = (const float*)d_in[3];
    const float* convv = (const float*)d_in[4];
    const float* convh = (const float*)d_in[5];
    const float* bng   = (const float*)d_in[6];
    const float* bnb   = (const float*)d_in[7];
    const float* fchw  = (const float*)d_in[8];
    const float* fchb  = (const float*)d_in[9];
    const float* fcvw  = (const float*)d_in[10];
    const float* fcvb  = (const float*)d_in[11];
    float* out = (float*)d_out;

    char* ws = (char*)d_ws;
    // layout (bytes):
    // s16    @ 0          13,107,200   fp16 spikes, pre-swizzled granules
    // smean  @ 13107200    6,553,600
    // y      @ 19660800   41,779,200
    // whl    @ 61440000   10,649,600   fp16 hi/lo weights [52][50][16][128], zero-padded
    // statm  @ 72089600        1,600
    // stats_ @ 72091200        1,600
    // ps     @ 72092800      409,600
    // psum   @ 72502400       25,600
    // vm     @ 72528000      524,288   -> total 73,052,288
    _Float16* s16  = (_Float16*)(ws);
    float* smean   = (float*)(ws + 13107200LL);
    float* y       = (float*)(ws + 19660800LL);
    _Float16* whl  = (_Float16*)(ws + 61440000LL);
    float* statm   = (float*)(ws + 72089600LL);
    float* stats_  = (float*)(ws + 72091200LL);
    float* ps      = (float*)(ws + 72092800LL);
    float* psum    = (float*)(ws + 72502400LL);
    float* vm      = (float*)(ws + 72528000LL);

    hipFuncSetAttribute(reinterpret_cast<const void*>(&k2u<4>),
        hipFuncAttributeMaxDynamicSharedMemorySize, 118784);
    hipFuncSetAttribute(reinterpret_cast<const void*>(&k2u<3>),
        hipFuncAttributeMaxDynamicSharedMemorySize, 118784);
    hipFuncSetAttribute(reinterpret_cast<const void*>(&k2u<2>),
        hipFuncAttributeMaxDynamicSharedMemorySize, 118784);
    hipFuncSetAttribute(reinterpret_cast<const void*>(&k2t),
        hipFuncAttributeMaxDynamicSharedMemorySize, 118784);

    k0_wsplit<<<dim3(50, 52), 256, 0, stream>>>(convh, whl);
    k1_embed_ln_lif<<<B_ * L_, 128, 0, stream>>>(item, tab, lng, lnb, s16, smean);
    k2u<4><<<dim3(128, 1), 512, 118784, stream>>>(s16, whl, y, 0);   // scales 0-3
    k2u<3><<<dim3(128, 4), 512, 118784, stream>>>(s16, whl, y, 1);   // scales 4-19
    k2u<2><<<dim3(128, 4), 512, 118784, stream>>>(s16, whl, y, 5);   // scales 20-35
    k2t<<<dim3(128, 4), 512, 118784, stream>>>(s16, whl, y);         // scales 36-49
    k3_partial<<<dim3(400, 8), 256, 0, stream>>>(y, psum);
    k3_final<<<dim3(2, 1), 256, 0, stream>>>(psum, bng, statm, stats_);
    k4_bn_lif_pool<<<dim3(B_, L_), 512, 0, stream>>>(y, statm, stats_, bnb, ps);
    k_vm<<<B_, 128, 0, stream>>>(smean, convv, vm);
    k5b<<<B_ / NB5, 128, 0, stream>>>(vm, ps, fchw, fchb, fcvw, fcvb, out);
}

// Round 14
// 275.597 us; speedup vs baseline: 1.2300x; 1.2300x over previous
//
#include <hip/hip_runtime.h>

#define B_ 256
#define L_ 50
#define D_ 128
#define T_ 4
#define NH 8
#define NV 4
#define TB_ (T_*B_)
#define EPSF 1e-5f

typedef _Float16 h8 __attribute__((ext_vector_type(8)));
typedef float f4 __attribute__((ext_vector_type(4)));

__device__ __forceinline__ float waveSum(float v) {
    #pragma unroll
    for (int o = 32; o > 0; o >>= 1) v += __shfl_down(v, o, 64);
    return v;
}

// element offset of scale i inside y buffer: 1024*8*sum_{i'<i}(50-i')
__device__ __forceinline__ size_t yoff(int i) {
    return (size_t)8192 * (size_t)(50 * i - (i * (i - 1)) / 2);
}

// K0: split conv_h_w fp32 -> fp16 (hi | lo*1024), [i][dk][c=16][d] with
// 16B-granule pre-swizzle (granule gd stored at gd^c); zero-pad dk>i, i>=50.
__global__ __launch_bounds__(256) void k0_wsplit(
        const float* __restrict__ w, _Float16* __restrict__ whl) {
    int dk = blockIdx.x, i = blockIdx.y;
    int t = threadIdx.x;
    int c = t >> 4, gd = t & 15;
    int h = c & 7;
    bool live = (i < 50) && (dk <= i);
    const float* src = w + (((size_t)i * NH + h) * L_ + dk) * D_ + gd * 8;
    h8 o;
    #pragma unroll
    for (int e = 0; e < 8; ++e) {
        float wv = live ? src[e] : 0.f;
        _Float16 hi = (_Float16)wv;
        o[e] = (c < 8) ? hi : (_Float16)((wv - (float)hi) * 1024.f);
    }
    *(h8*)(whl + (((size_t)i * 50 + dk) * 16 + c) * 128 + ((gd ^ c) & 15) * 8) = o;
}

// K1: embedding + LayerNorm + LIF(T=4) -> s16 [T*B][L][D] fp16 PRE-SWIZZLED, smean fp32
__global__ __launch_bounds__(128) void k1_embed_ln_lif(
        const int* __restrict__ item, const float* __restrict__ tab,
        const float* __restrict__ g, const float* __restrict__ be,
        _Float16* __restrict__ s16, float* __restrict__ smean) {
    int bid = blockIdx.x;
    int b = bid / L_, l = bid % L_;
    int d = threadIdx.x;
    int wid = d >> 6, lane = d & 63;
    __shared__ float red[2];
    int it = item[b * L_ + l];
    float e = tab[(size_t)it * D_ + d];
    float sm_ = waveSum(e);
    if (lane == 0) red[wid] = sm_;
    __syncthreads();
    float mu = (red[0] + red[1]) * (1.f / 128.f);
    __syncthreads();
    float df = e - mu;
    float s2 = waveSum(df * df);
    if (lane == 0) red[wid] = s2;
    __syncthreads();
    float var = (red[0] + red[1]) * (1.f / 128.f);
    float x = df / sqrtf(var + EPSF) * g[d] + be[d];
    float v = 0.f, acc = 0.f;
    int pos = (((d >> 3) ^ l) & 15) * 8 + (d & 7);   // pre-swizzled slot
    #pragma unroll
    for (int t = 0; t < T_; ++t) {
        v += (x - v) * 0.5f;
        float sp = (v >= 1.f) ? 1.f : 0.f;
        v *= (1.f - sp);
        s16[((size_t)(t * B_ + b) * L_ + l) * D_ + pos] = (_Float16)sp;
        acc += sp;
    }
    smean[((size_t)b * L_ + l) * D_ + d] = acc * 0.25f;
}

// ---- K2u: unified scale-group conv (round-6 structure + jmode j-window split).
// 512 threads = 8 waves, 8 tb/block. Wave = (tb-pair p, dc-half dh).
// LDS: A 102400 + B slot 16KB. jmode=0: grp=gbase+blockIdx.y, joff=0.
// jmode=1: grp=gbase, joff=2*blockIdx.y (j-window split; used for group 0 so
// the dispatch fills all 256 CUs). Zero-padded whl keeps clamped rows exact.
template<int MTG>
__global__ __launch_bounds__(512, 2) void k2u(
        const _Float16* __restrict__ s16, const _Float16* __restrict__ whl,
        float* __restrict__ y, int gbase, int jmode) {
    extern __shared__ __align__(16) char lds[];
    char* Bslot = lds + 102400;
    const int NM = 2 * MTG;
    const int tbo = blockIdx.x;              // 8 tb per block
    const int grp = jmode ? gbase : (gbase + blockIdx.y);
    const int joff = jmode ? 2 * blockIdx.y : 0;
    const int i0 = grp * 4;
    const int kmax = i0 + 4;
    const int tid = threadIdx.x;
    const int wave = tid >> 6, lane = tid & 63;
    const int p = wave >> 1;                 // tb-pair 0..3
    const int dh = wave & 1;                 // dc half 0/1
    const int c_ = lane & 15, g = lane >> 4;

    // stage A (linear copy; swizzle baked into s16)
    {
        const float4* src = (const float4*)(s16 + (size_t)tbo * 8 * (L_ * D_));
        float4* dst = (float4*)lds;
        for (int idx = tid; idx < 6400; idx += 512) dst[idx] = src[idx];
    }
    // B thread slots: bytes [o0,o0+16) and [o1,o1+16) of the 16KB dk-chunk
    const char* bsrc = (const char*)whl + (size_t)i0 * 50 * 4096;
    const int o0 = tid * 16, o1 = 8192 + tid * 16;
    const int sc0 = o0 >> 12, r0 = o0 & 4095;
    const int sc1 = o1 >> 12, r1 = o1 & 4095;
    const char* g0p = bsrc + (size_t)sc0 * (50 * 4096) + r0;
    const char* g1p = bsrc + (size_t)sc1 * (50 * 4096) + r1;

    float4 n0 = *(const float4*)(g0p);
    float4 n1 = *(const float4*)(g1p);
    __syncthreads();                      // A visible
    *(float4*)(Bslot + o0) = n0;
    *(float4*)(Bslot + o1) = n1;
    __syncthreads();

    f4 acc[4][NM];
    #pragma unroll
    for (int sc = 0; sc < 4; ++sc)
        #pragma unroll
        for (int m = 0; m < NM; ++m) { f4 z = {0.f, 0.f, 0.f, 0.f}; acc[sc][m] = z; }

    for (int dk = 0; dk < kmax; ++dk) {
        const bool more = (dk + 1 < kmax);
        float4 m0, m1;
        if (more) {
            m0 = *(const float4*)(g0p + (size_t)(dk + 1) * 4096);
            m1 = *(const float4*)(g1p + (size_t)(dk + 1) * 4096);
        }
        __builtin_amdgcn_sched_barrier(0);   // keep loads issued before consume
        #pragma unroll
        for (int dci = 0; dci < 2; ++dci) {
            const int dc = dh * 2 + dci;
            h8 bf[4];
            #pragma unroll
            for (int sc = 0; sc < 4; ++sc)
                bf[sc] = *(const h8*)(Bslot + sc * 4096 + c_ * 256 +
                                      ((((dc << 2) + g) ^ c_) & 15) * 16);
            #pragma unroll
            for (int m = 0; m < NM; ++m) {
                const int tbL = p * 2 + (m >= MTG ? 1 : 0);
                const int jt = joff + ((m >= MTG) ? m - MTG : m);
                int l = jt * 16 + c_ + dk; if (l > 49) l = 49;  // only zero-w rows clamp
                h8 a = *(const h8*)(lds + tbL * 12800 + l * 256 +
                                    ((((dc << 2) + g) ^ l) & 15) * 16);
                #pragma unroll
                for (int sc = 0; sc < 4; ++sc)
                    acc[sc][m] = __builtin_amdgcn_mfma_f32_16x16x32_f16(a, bf[sc], acc[sc][m], 0, 0, 0);
            }
        }
        __syncthreads();
        if (more) {
            *(float4*)(Bslot + o0) = m0;
            *(float4*)(Bslot + o1) = m1;
        }
        __syncthreads();
    }

    // merge dc-halves: dh=1 writes, dh=0 adds. Padded stride vs bank aliasing.
    const int STR = 2 * NM * 4 + 4;          // floats
    float* mbuf = (float*)lds;               // reuse A region
    #pragma unroll
    for (int half = 0; half < 2; ++half) {
        __syncthreads();
        if (dh == 1) {
            float* wp = mbuf + (size_t)(p * 64 + lane) * STR;
            #pragma unroll
            for (int sc = 0; sc < 2; ++sc)
                #pragma unroll
                for (int m = 0; m < NM; ++m)
                    *(f4*)(wp + (sc * NM + m) * 4) = acc[2 * half + sc][m];
        }
        __syncthreads();
        if (dh == 0) {
            const float* rp = mbuf + (size_t)(p * 64 + lane) * STR;
            #pragma unroll
            for (int sc = 0; sc < 2; ++sc)
                #pragma unroll
                for (int m = 0; m < NM; ++m)
                    acc[2 * half + sc][m] += *(const f4*)(rp + (sc * NM + m) * 4);
        }
    }

    if (dh == 0) {
        const bool hiLane = (c_ < 8);
        const int h = c_ & 7;
        #pragma unroll
        for (int sc = 0; sc < 4; ++sc) {
            const int i = i0 + sc;
            const int J = 50 - i;
            #pragma unroll
            for (int m = 0; m < NM; ++m) {
                const int tbL = p * 2 + (m >= MTG ? 1 : 0);
                const int jt = joff + ((m >= MTG) ? m - MTG : m);
                const int tb = tbo * 8 + tbL;
                size_t yb = yoff(i) + ((size_t)tb * NH + h) * J;
                #pragma unroll
                for (int r = 0; r < 4; ++r) {
                    float lo = __shfl_xor(acc[sc][m][r], 8, 64);
                    int j = jt * 16 + g * 4 + r;
                    if (hiLane && j < J) y[yb + j] = acc[sc][m][r] + lo * (1.f / 1024.f);
                }
            }
        }
    }
}

// ---- K2t (round-6 verbatim): tail scales (i>=36), wave box (4 tb, 4 sc, 1 dc).
__global__ __launch_bounds__(512, 2) void k2t(
        const _Float16* __restrict__ s16, const _Float16* __restrict__ whl,
        float* __restrict__ y) {
    extern __shared__ __align__(16) char lds[];
    char* Bslot = lds + 102400;
    const int tbo = blockIdx.x;              // 8 tb per block
    const int i0 = 36 + blockIdx.y * 4;      // 36,40,44,48 (scales 50,51 zero-padded)
    const int kmax = (i0 + 4 <= 50) ? (i0 + 4) : 50;
    const int tid = threadIdx.x;
    const int wave = tid >> 6, lane = tid & 63;
    const int tq = wave >> 2;                // tb-quad 0/1
    const int dc = wave & 3;                 // dc slice 0..3
    const int c_ = lane & 15, g = lane >> 4;

    {
        const float4* src = (const float4*)(s16 + (size_t)tbo * 8 * (L_ * D_));
        float4* dst = (float4*)lds;
        for (int idx = tid; idx < 6400; idx += 512) dst[idx] = src[idx];
    }
    const char* bsrc = (const char*)whl + (size_t)i0 * 204800;
    const int o0 = tid * 16, o1 = 8192 + tid * 16;
    const char* g0p = bsrc + (size_t)(o0 >> 12) * 204800 + (o0 & 4095);
    const char* g1p = bsrc + (size_t)(o1 >> 12) * 204800 + (o1 & 4095);
    float4 n0 = *(const float4*)(g0p);
    float4 n1 = *(const float4*)(g1p);
    __syncthreads();
    *(float4*)(Bslot + o0) = n0;
    *(float4*)(Bslot + o1) = n1;
    __syncthreads();

    f4 acc[4][4];                            // [sc][tt]
    #pragma unroll
    for (int sc = 0; sc < 4; ++sc)
        #pragma unroll
        for (int tt = 0; tt < 4; ++tt) { f4 z = {0.f, 0.f, 0.f, 0.f}; acc[sc][tt] = z; }

    const int boffc = c_ * 256 + ((((dc << 2) + g) ^ c_) & 15) * 16;
    for (int dk = 0; dk < kmax; ++dk) {
        const bool more = (dk + 1 < kmax);
        float4 m0, m1;
        if (more) {
            m0 = *(const float4*)(g0p + (size_t)(dk + 1) * 4096);
            m1 = *(const float4*)(g1p + (size_t)(dk + 1) * 4096);
        }
        __builtin_amdgcn_sched_barrier(0);
        h8 bf[4];
        #pragma unroll
        for (int sc = 0; sc < 4; ++sc)
            bf[sc] = *(const h8*)(Bslot + sc * 4096 + boffc);
        int l = c_ + dk; if (l > 49) l = 49;  // fires only where w==0
        const int aoff = l * 256 + ((((dc << 2) + g) ^ l) & 15) * 16;
        #pragma unroll
        for (int tt = 0; tt < 4; ++tt) {
            h8 a = *(const h8*)(lds + (tq * 4 + tt) * 12800 + aoff);
            #pragma unroll
            for (int sc = 0; sc < 4; ++sc)
                acc[sc][tt] = __builtin_amdgcn_mfma_f32_16x16x32_f16(a, bf[sc], acc[sc][tt], 0, 0, 0);
        }
        __syncthreads();
        if (more) {
            *(float4*)(Bslot + o0) = m0;
            *(float4*)(Bslot + o1) = m1;
        }
        __syncthreads();
    }

    // merge K-partials across dc=1..3 into dc=0 (A region dead now).
    f4* mbuf = (f4*)lds;
    if (dc != 0) {
        f4* wp = mbuf + (size_t)(((dc - 1) * 2 + tq) * 16) * 64 + lane;
        #pragma unroll
        for (int sc = 0; sc < 4; ++sc)
            #pragma unroll
            for (int tt = 0; tt < 4; ++tt)
                wp[(sc * 4 + tt) * 64] = acc[sc][tt];
    }
    __syncthreads();
    if (dc == 0) {
        #pragma unroll
        for (int dd = 0; dd < 3; ++dd) {
            const f4* rp = mbuf + (size_t)((dd * 2 + tq) * 16) * 64 + lane;
            #pragma unroll
            for (int sc = 0; sc < 4; ++sc)
                #pragma unroll
                for (int tt = 0; tt < 4; ++tt)
                    acc[sc][tt] += rp[(sc * 4 + tt) * 64];
        }
        const bool hiLane = (c_ < 8);
        const int h = c_ & 7;
        #pragma unroll
        for (int sc = 0; sc < 4; ++sc) {
            const int i = i0 + sc;
            const int J = 50 - i;
            if (J <= 0) continue;
            #pragma unroll
            for (int tt = 0; tt < 4; ++tt) {
                const int tb = tbo * 8 + tq * 4 + tt;
                size_t yb = yoff(i) + ((size_t)tb * NH + h) * J;
                #pragma unroll
                for (int r = 0; r < 4; ++r) {
                    float lo = __shfl_xor(acc[sc][tt][r], 8, 64);
                    int j = g * 4 + r;
                    if (hiLane && j < J) y[yb + j] = acc[sc][tt][r] + lo * (1.f / 1024.f);
                }
            }
        }
    }
}

// K3: BN stats, two stage (partial over 128-tb chunks, then final)
__global__ __launch_bounds__(256) void k3_partial(
        const float* __restrict__ y, float* __restrict__ psum) {
    int ih = blockIdx.x, ck = blockIdx.y;
    int i = ih >> 3, h = ih & 7;
    int J = 50 - i;
    size_t yb = yoff(i);
    int tid = threadIdx.x;
    int grp = tid >> 5, sub = tid & 31;
    float sm = 0.f, ss = 0.f;
    for (int tb = ck * 128 + grp; tb < (ck + 1) * 128; tb += 8) {
        const float* row = y + yb + ((size_t)tb * NH + h) * J;
        for (int j = sub; j < J; j += 32) { float v = row[j]; sm += v; ss += v * v; }
    }
    __shared__ float r1[4], r2[4];
    float a = waveSum(sm), b = waveSum(ss);
    int wid = tid >> 6, lane = tid & 63;
    if (lane == 0) { r1[wid] = a; r2[wid] = b; }
    __syncthreads();
    if (tid == 0) {
        psum[((size_t)ih * 8 + ck) * 2]     = r1[0] + r1[1] + r1[2] + r1[3];
        psum[((size_t)ih * 8 + ck) * 2 + 1] = r2[0] + r2[1] + r2[2] + r2[3];
    }
}

__global__ __launch_bounds__(256) void k3_final(
        const float* __restrict__ psum, const float* __restrict__ bng,
        float* __restrict__ statm, float* __restrict__ stats_) {
    int ih = blockIdx.x * 256 + threadIdx.x;
    if (ih >= 400) return;
    float S = 0.f, Q = 0.f;
    for (int ck = 0; ck < 8; ++ck) {
        S += psum[((size_t)ih * 8 + ck) * 2];
        Q += psum[((size_t)ih * 8 + ck) * 2 + 1];
    }
    int i = ih >> 3;
    float cnt = 1024.f * (float)(50 - i);
    float m = S / cnt;
    float var = Q / cnt - m * m; if (var < 0.f) var = 0.f;
    statm[ih] = m;
    stats_[ih] = bng[ih] / sqrtf(var + EPSF);
}

// K4: BN + LIF over t + max-pool over j -> poolsum [B,400]
__global__ __launch_bounds__(512) void k4_bn_lif_pool(
        const float* __restrict__ y, const float* __restrict__ statm,
        const float* __restrict__ stats_, const float* __restrict__ bnb,
        float* __restrict__ ps) {
    int b = blockIdx.x, i = blockIdx.y, J = L_ - i;
    int h = threadIdx.x >> 6, lane = threadIdx.x & 63;
    int ih = i * NH + h;
    float m = statm[ih], sc = stats_[ih], bb = bnb[ih];
    size_t yb = yoff(i);
    bool valid = lane < J;
    float v = 0.f; int cnt = 0;
    #pragma unroll
    for (int t = 0; t < T_; ++t) {
        int tb = t * B_ + b;
        float yn;
        if (valid) {
            float raw = y[yb + ((size_t)tb * NH + h) * J + lane];
            yn = (raw - m) * sc + bb;
        } else yn = -1e30f;
        v += (yn - v) * 0.5f;
        bool sp = (v >= 1.f);
        if (sp) v = 0.f;
        if (__any(sp)) cnt++;
    }
    if (lane == 0) ps[(size_t)b * 400 + ih] = (float)cnt;
}

// K5 (round-6 verbatim): per-b fused heads
__global__ __launch_bounds__(128) void k5_final(
        const float* __restrict__ smean, const float* __restrict__ ps,
        const float* __restrict__ convv, const float* __restrict__ fchw,
        const float* __restrict__ fchb, const float* __restrict__ fcvw,
        const float* __restrict__ fcvb, float* __restrict__ out) {
    __shared__ float sm_l[L_ * D_];
    __shared__ float vm[NV * D_];
    __shared__ float ps_l[400];
    int b = blockIdx.x, tid = threadIdx.x;
    for (int idx = tid; idx < L_ * D_; idx += 128) sm_l[idx] = smean[(size_t)b * (L_ * D_) + idx];
    for (int idx = tid; idx < 400; idx += 128) ps_l[idx] = ps[(size_t)b * 400 + idx];
    __syncthreads();
    int d = tid;
    #pragma unroll
    for (int c = 0; c < NV; ++c) {
        float a = 0.f;
        for (int l = 0; l < L_; ++l) a += convv[c * L_ + l] * sm_l[l * D_ + d];
        vm[c * D_ + d] = a;
    }
    __syncthreads();
    float acc = fchb[d] + fcvb[d];
    float ah = 0.f;
    for (int ih = 0; ih < 400; ++ih) ah += ps_l[ih] * fchw[d * 400 + ih];
    acc += ah * 0.25f;
    float av = 0.f;
    for (int cd = 0; cd < NV * D_; ++cd) av += vm[cd] * fcvw[d * (NV * D_) + cd];
    acc += av;
    out[(size_t)b * D_ + d] = acc;
}

extern "C" void kernel_launch(void* const* d_in, const int* in_sizes, int n_in,
                              void* d_out, int out_size, void* d_ws, size_t ws_size,
                              hipStream_t stream) {
    const int*   item  = (const int*)d_in[0];
    const float* tab   = (const float*)d_in[1];
    const float* lng   = (const float*)d_in[2];
    const float* lnb   = (const float*)d_in[3];
    const float* convv = (const float*)d_in[4];
    const float* convh = (const float*)d_in[5];
    const float* bng   = (const float*)d_in[6];
    const float* bnb   = (const float*)d_in[7];
    const float* fchw  = (const float*)d_in[8];
    const float* fchb  = (const float*)d_in[9];
    const float* fcvw  = (const float*)d_in[10];
    const float* fcvb  = (const float*)d_in[11];
    float* out = (float*)d_out;

    char* ws = (char*)d_ws;
    // layout (bytes):
    // s16    @ 0          13,107,200   fp16 spikes, pre-swizzled granules
    // smean  @ 13107200    6,553,600
    // y      @ 19660800   41,779,200
    // whl    @ 61440000   10,649,600   fp16 hi/lo weights [52][50][16][128], zero-padded
    // statm  @ 72089600        1,600
    // stats_ @ 72091200        1,600
    // ps     @ 72092800      409,600
    // psum   @ 72502400       25,600   -> total 72,528,000
    _Float16* s16  = (_Float16*)(ws);
    float* smean   = (float*)(ws + 13107200LL);
    float* y       = (float*)(ws + 19660800LL);
    _Float16* whl  = (_Float16*)(ws + 61440000LL);
    float* statm   = (float*)(ws + 72089600LL);
    float* stats_  = (float*)(ws + 72091200LL);
    float* ps      = (float*)(ws + 72092800LL);
    float* psum    = (float*)(ws + 72502400LL);

    hipFuncSetAttribute(reinterpret_cast<const void*>(&k2u<3>),
        hipFuncAttributeMaxDynamicSharedMemorySize, 118784);
    hipFuncSetAttribute(reinterpret_cast<const void*>(&k2u<2>),
        hipFuncAttributeMaxDynamicSharedMemorySize, 118784);
    hipFuncSetAttribute(reinterpret_cast<const void*>(&k2t),
        hipFuncAttributeMaxDynamicSharedMemorySize, 118784);

    k0_wsplit<<<dim3(50, 52), 256, 0, stream>>>(convh, whl);
    k1_embed_ln_lif<<<B_ * L_, 128, 0, stream>>>(item, tab, lng, lnb, s16, smean);
    // group 0 split into two j-windows -> 256 blocks (full machine):
    k2u<2><<<dim3(128, 2), 512, 118784, stream>>>(s16, whl, y, 0, 1);  // g0, j 0-31 / 32-63
    k2u<3><<<dim3(128, 4), 512, 118784, stream>>>(s16, whl, y, 1, 0);  // scales 4-19
    k2u<2><<<dim3(128, 4), 512, 118784, stream>>>(s16, whl, y, 5, 0);  // scales 20-35
    k2t<<<dim3(128, 4), 512, 118784, stream>>>(s16, whl, y);           // scales 36-49
    k3_partial<<<dim3(400, 8), 256, 0, stream>>>(y, psum);
    k3_final<<<dim3(2, 1), 256, 0, stream>>>(psum, bng, statm, stats_);
    k4_bn_lif_pool<<<dim3(B_, L_), 512, 0, stream>>>(y, statm, stats_, bnb, ps);
    k5_final<<<B_, 128, 0, stream>>>(smean, ps, convv, fchw, fchb, fcvw, fcvb, out);
}

// Round 15
// 273.408 us; speedup vs baseline: 1.2399x; 1.0080x over previous
//
#include <hip/hip_runtime.h>

#define B_ 256
#define L_ 50
#define D_ 128
#define T_ 4
#define NH 8
#define NV 4
#define TB_ (T_*B_)
#define EPSF 1e-5f

typedef _Float16 h8 __attribute__((ext_vector_type(8)));
typedef float f4 __attribute__((ext_vector_type(4)));

__device__ __forceinline__ float waveSum(float v) {
    #pragma unroll
    for (int o = 32; o > 0; o >>= 1) v += __shfl_down(v, o, 64);
    return v;
}

// element offset of scale i inside y buffer: 1024*8*sum_{i'<i}(50-i')
__device__ __forceinline__ size_t yoff(int i) {
    return (size_t)8192 * (size_t)(50 * i - (i * (i - 1)) / 2);
}

// K0: split conv_h_w fp32 -> fp16 (hi | lo*1024), [i][dk][c=16][d] with
// 16B-granule pre-swizzle (granule gd stored at gd^c); zero-pad dk>i, i>=50.
__global__ __launch_bounds__(256) void k0_wsplit(
        const float* __restrict__ w, _Float16* __restrict__ whl) {
    int dk = blockIdx.x, i = blockIdx.y;
    int t = threadIdx.x;
    int c = t >> 4, gd = t & 15;
    int h = c & 7;
    bool live = (i < 50) && (dk <= i);
    const float* src = w + (((size_t)i * NH + h) * L_ + dk) * D_ + gd * 8;
    h8 o;
    #pragma unroll
    for (int e = 0; e < 8; ++e) {
        float wv = live ? src[e] : 0.f;
        _Float16 hi = (_Float16)wv;
        o[e] = (c < 8) ? hi : (_Float16)((wv - (float)hi) * 1024.f);
    }
    *(h8*)(whl + (((size_t)i * 50 + dk) * 16 + c) * 128 + ((gd ^ c) & 15) * 8) = o;
}

// K1: embedding + LayerNorm + LIF(T=4) -> s16 [T*B][L][D] fp16 PRE-SWIZZLED, smean fp32
__global__ __launch_bounds__(128) void k1_embed_ln_lif(
        const int* __restrict__ item, const float* __restrict__ tab,
        const float* __restrict__ g, const float* __restrict__ be,
        _Float16* __restrict__ s16, float* __restrict__ smean) {
    int bid = blockIdx.x;
    int b = bid / L_, l = bid % L_;
    int d = threadIdx.x;
    int wid = d >> 6, lane = d & 63;
    __shared__ float red[2];
    int it = item[b * L_ + l];
    float e = tab[(size_t)it * D_ + d];
    float sm_ = waveSum(e);
    if (lane == 0) red[wid] = sm_;
    __syncthreads();
    float mu = (red[0] + red[1]) * (1.f / 128.f);
    __syncthreads();
    float df = e - mu;
    float s2 = waveSum(df * df);
    if (lane == 0) red[wid] = s2;
    __syncthreads();
    float var = (red[0] + red[1]) * (1.f / 128.f);
    float x = df / sqrtf(var + EPSF) * g[d] + be[d];
    float v = 0.f, acc = 0.f;
    int pos = (((d >> 3) ^ l) & 15) * 8 + (d & 7);   // pre-swizzled slot
    #pragma unroll
    for (int t = 0; t < T_; ++t) {
        v += (x - v) * 0.5f;
        float sp = (v >= 1.f) ? 1.f : 0.f;
        v *= (1.f - sp);
        s16[((size_t)(t * B_ + b) * L_ + l) * D_ + pos] = (_Float16)sp;
        acc += sp;
    }
    smean[((size_t)b * L_ + l) * D_ + d] = acc * 0.25f;
}

// ---- K2u: unified scale-group conv (r6 structure + LPT job ordering).
// 512 threads = 8 waves, 8 tb/block. Wave = (tb-pair p, dc-half dh).
// LDS: A 102400 + B slot 16KB -> 1 block/CU.
// jmode 0: grp = gbase + (gridDim.y-1-y)  (LPT: longest kmax first), joff=0.
// jmode 1: grp = gbase, joff = 2*y (j-window split).
// jmode 2: y<4 -> grp = 8-y (g8,g7,g6,g5), joff=0; y>=4 -> grp=0, joff=2*(y-4).
// Zero-padded whl keeps clamped rows exact.
template<int MTG>
__global__ __launch_bounds__(512, 2) void k2u(
        const _Float16* __restrict__ s16, const _Float16* __restrict__ whl,
        float* __restrict__ y, int gbase, int jmode) {
    extern __shared__ __align__(16) char lds[];
    char* Bslot = lds + 102400;
    const int NM = 2 * MTG;
    const int tbo = blockIdx.x;              // 8 tb per block
    int grp, joff;
    if (jmode == 0) { grp = gbase + (gridDim.y - 1 - blockIdx.y); joff = 0; }
    else if (jmode == 1) { grp = gbase; joff = 2 * blockIdx.y; }
    else {
        if (blockIdx.y < 4) { grp = 8 - blockIdx.y; joff = 0; }
        else { grp = 0; joff = 2 * (blockIdx.y - 4); }
    }
    const int i0 = grp * 4;
    const int kmax = i0 + 4;
    const int tid = threadIdx.x;
    const int wave = tid >> 6, lane = tid & 63;
    const int p = wave >> 1;                 // tb-pair 0..3
    const int dh = wave & 1;                 // dc half 0/1
    const int c_ = lane & 15, g = lane >> 4;

    // stage A (linear copy; swizzle baked into s16)
    {
        const float4* src = (const float4*)(s16 + (size_t)tbo * 8 * (L_ * D_));
        float4* dst = (float4*)lds;
        for (int idx = tid; idx < 6400; idx += 512) dst[idx] = src[idx];
    }
    // B thread slots: bytes [o0,o0+16) and [o1,o1+16) of the 16KB dk-chunk
    const char* bsrc = (const char*)whl + (size_t)i0 * 50 * 4096;
    const int o0 = tid * 16, o1 = 8192 + tid * 16;
    const int sc0 = o0 >> 12, r0 = o0 & 4095;
    const int sc1 = o1 >> 12, r1 = o1 & 4095;
    const char* g0p = bsrc + (size_t)sc0 * (50 * 4096) + r0;
    const char* g1p = bsrc + (size_t)sc1 * (50 * 4096) + r1;

    float4 n0 = *(const float4*)(g0p);
    float4 n1 = *(const float4*)(g1p);
    __syncthreads();                      // A visible
    *(float4*)(Bslot + o0) = n0;
    *(float4*)(Bslot + o1) = n1;
    __syncthreads();

    f4 acc[4][NM];
    #pragma unroll
    for (int sc = 0; sc < 4; ++sc)
        #pragma unroll
        for (int m = 0; m < NM; ++m) { f4 z = {0.f, 0.f, 0.f, 0.f}; acc[sc][m] = z; }

    for (int dk = 0; dk < kmax; ++dk) {
        const bool more = (dk + 1 < kmax);
        float4 m0, m1;
        if (more) {
            m0 = *(const float4*)(g0p + (size_t)(dk + 1) * 4096);
            m1 = *(const float4*)(g1p + (size_t)(dk + 1) * 4096);
        }
        __builtin_amdgcn_sched_barrier(0);   // keep loads issued before consume
        #pragma unroll
        for (int dci = 0; dci < 2; ++dci) {
            const int dc = dh * 2 + dci;
            h8 bf[4];
            #pragma unroll
            for (int sc = 0; sc < 4; ++sc)
                bf[sc] = *(const h8*)(Bslot + sc * 4096 + c_ * 256 +
                                      ((((dc << 2) + g) ^ c_) & 15) * 16);
            #pragma unroll
            for (int m = 0; m < NM; ++m) {
                const int tbL = p * 2 + (m >= MTG ? 1 : 0);
                const int jt = joff + ((m >= MTG) ? m - MTG : m);
                int l = jt * 16 + c_ + dk; if (l > 49) l = 49;  // only zero-w rows clamp
                h8 a = *(const h8*)(lds + tbL * 12800 + l * 256 +
                                    ((((dc << 2) + g) ^ l) & 15) * 16);
                #pragma unroll
                for (int sc = 0; sc < 4; ++sc)
                    acc[sc][m] = __builtin_amdgcn_mfma_f32_16x16x32_f16(a, bf[sc], acc[sc][m], 0, 0, 0);
            }
        }
        __syncthreads();
        if (more) {
            *(float4*)(Bslot + o0) = m0;
            *(float4*)(Bslot + o1) = m1;
        }
        __syncthreads();
    }

    // merge dc-halves: dh=1 writes, dh=0 adds. Padded stride vs bank aliasing.
    const int STR = 2 * NM * 4 + 4;          // floats
    float* mbuf = (float*)lds;               // reuse A region
    #pragma unroll
    for (int half = 0; half < 2; ++half) {
        __syncthreads();
        if (dh == 1) {
            float* wp = mbuf + (size_t)(p * 64 + lane) * STR;
            #pragma unroll
            for (int sc = 0; sc < 2; ++sc)
                #pragma unroll
                for (int m = 0; m < NM; ++m)
                    *(f4*)(wp + (sc * NM + m) * 4) = acc[2 * half + sc][m];
        }
        __syncthreads();
        if (dh == 0) {
            const float* rp = mbuf + (size_t)(p * 64 + lane) * STR;
            #pragma unroll
            for (int sc = 0; sc < 2; ++sc)
                #pragma unroll
                for (int m = 0; m < NM; ++m)
                    acc[2 * half + sc][m] += *(const f4*)(rp + (sc * NM + m) * 4);
        }
    }

    if (dh == 0) {
        const bool hiLane = (c_ < 8);
        const int h = c_ & 7;
        #pragma unroll
        for (int sc = 0; sc < 4; ++sc) {
            const int i = i0 + sc;
            const int J = 50 - i;
            #pragma unroll
            for (int m = 0; m < NM; ++m) {
                const int tbL = p * 2 + (m >= MTG ? 1 : 0);
                const int jt = joff + ((m >= MTG) ? m - MTG : m);
                const int tb = tbo * 8 + tbL;
                size_t yb = yoff(i) + ((size_t)tb * NH + h) * J;
                #pragma unroll
                for (int r = 0; r < 4; ++r) {
                    float lo = __shfl_xor(acc[sc][m][r], 8, 64);
                    int j = jt * 16 + g * 4 + r;
                    if (hiLane && j < J) y[yb + j] = acc[sc][m][r] + lo * (1.f / 1024.f);
                }
            }
        }
    }
}

// ---- K2t: tail scales (i>=36), wave box (4 tb, 4 sc, 1 dc), LPT y-order.
__global__ __launch_bounds__(512, 2) void k2t(
        const _Float16* __restrict__ s16, const _Float16* __restrict__ whl,
        float* __restrict__ y) {
    extern __shared__ __align__(16) char lds[];
    char* Bslot = lds + 102400;
    const int tbo = blockIdx.x;              // 8 tb per block
    const int i0 = 36 + (3 - blockIdx.y) * 4;  // LPT: 48,44,40,36 (50/51 zero-padded)
    const int kmax = (i0 + 4 <= 50) ? (i0 + 4) : 50;
    const int tid = threadIdx.x;
    const int wave = tid >> 6, lane = tid & 63;
    const int tq = wave >> 2;                // tb-quad 0/1
    const int dc = wave & 3;                 // dc slice 0..3
    const int c_ = lane & 15, g = lane >> 4;

    {
        const float4* src = (const float4*)(s16 + (size_t)tbo * 8 * (L_ * D_));
        float4* dst = (float4*)lds;
        for (int idx = tid; idx < 6400; idx += 512) dst[idx] = src[idx];
    }
    const char* bsrc = (const char*)whl + (size_t)i0 * 204800;
    const int o0 = tid * 16, o1 = 8192 + tid * 16;
    const char* g0p = bsrc + (size_t)(o0 >> 12) * 204800 + (o0 & 4095);
    const char* g1p = bsrc + (size_t)(o1 >> 12) * 204800 + (o1 & 4095);
    float4 n0 = *(const float4*)(g0p);
    float4 n1 = *(const float4*)(g1p);
    __syncthreads();
    *(float4*)(Bslot + o0) = n0;
    *(float4*)(Bslot + o1) = n1;
    __syncthreads();

    f4 acc[4][4];                            // [sc][tt]
    #pragma unroll
    for (int sc = 0; sc < 4; ++sc)
        #pragma unroll
        for (int tt = 0; tt < 4; ++tt) { f4 z = {0.f, 0.f, 0.f, 0.f}; acc[sc][tt] = z; }

    const int boffc = c_ * 256 + ((((dc << 2) + g) ^ c_) & 15) * 16;
    for (int dk = 0; dk < kmax; ++dk) {
        const bool more = (dk + 1 < kmax);
        float4 m0, m1;
        if (more) {
            m0 = *(const float4*)(g0p + (size_t)(dk + 1) * 4096);
            m1 = *(const float4*)(g1p + (size_t)(dk + 1) * 4096);
        }
        __builtin_amdgcn_sched_barrier(0);
        h8 bf[4];
        #pragma unroll
        for (int sc = 0; sc < 4; ++sc)
            bf[sc] = *(const h8*)(Bslot + sc * 4096 + boffc);
        int l = c_ + dk; if (l > 49) l = 49;  // fires only where w==0
        const int aoff = l * 256 + ((((dc << 2) + g) ^ l) & 15) * 16;
        #pragma unroll
        for (int tt = 0; tt < 4; ++tt) {
            h8 a = *(const h8*)(lds + (tq * 4 + tt) * 12800 + aoff);
            #pragma unroll
            for (int sc = 0; sc < 4; ++sc)
                acc[sc][tt] = __builtin_amdgcn_mfma_f32_16x16x32_f16(a, bf[sc], acc[sc][tt], 0, 0, 0);
        }
        __syncthreads();
        if (more) {
            *(float4*)(Bslot + o0) = m0;
            *(float4*)(Bslot + o1) = m1;
        }
        __syncthreads();
    }

    // merge K-partials across dc=1..3 into dc=0 (A region dead now).
    f4* mbuf = (f4*)lds;
    if (dc != 0) {
        f4* wp = mbuf + (size_t)(((dc - 1) * 2 + tq) * 16) * 64 + lane;
        #pragma unroll
        for (int sc = 0; sc < 4; ++sc)
            #pragma unroll
            for (int tt = 0; tt < 4; ++tt)
                wp[(sc * 4 + tt) * 64] = acc[sc][tt];
    }
    __syncthreads();
    if (dc == 0) {
        #pragma unroll
        for (int dd = 0; dd < 3; ++dd) {
            const f4* rp = mbuf + (size_t)((dd * 2 + tq) * 16) * 64 + lane;
            #pragma unroll
            for (int sc = 0; sc < 4; ++sc)
                #pragma unroll
                for (int tt = 0; tt < 4; ++tt)
                    acc[sc][tt] += rp[(sc * 4 + tt) * 64];
        }
        const bool hiLane = (c_ < 8);
        const int h = c_ & 7;
        #pragma unroll
        for (int sc = 0; sc < 4; ++sc) {
            const int i = i0 + sc;
            const int J = 50 - i;
            if (J <= 0) continue;
            #pragma unroll
            for (int tt = 0; tt < 4; ++tt) {
                const int tb = tbo * 8 + tq * 4 + tt;
                size_t yb = yoff(i) + ((size_t)tb * NH + h) * J;
                #pragma unroll
                for (int r = 0; r < 4; ++r) {
                    float lo = __shfl_xor(acc[sc][tt][r], 8, 64);
                    int j = g * 4 + r;
                    if (hiLane && j < J) y[yb + j] = acc[sc][tt][r] + lo * (1.f / 1024.f);
                }
            }
        }
    }
}

// K3: BN stats, two stage (partial over 128-tb chunks, then final)
__global__ __launch_bounds__(256) void k3_partial(
        const float* __restrict__ y, float* __restrict__ psum) {
    int ih = blockIdx.x, ck = blockIdx.y;
    int i = ih >> 3, h = ih & 7;
    int J = 50 - i;
    size_t yb = yoff(i);
    int tid = threadIdx.x;
    int grp = tid >> 5, sub = tid & 31;
    float sm = 0.f, ss = 0.f;
    for (int tb = ck * 128 + grp; tb < (ck + 1) * 128; tb += 8) {
        const float* row = y + yb + ((size_t)tb * NH + h) * J;
        for (int j = sub; j < J; j += 32) { float v = row[j]; sm += v; ss += v * v; }
    }
    __shared__ float r1[4], r2[4];
    float a = waveSum(sm), b = waveSum(ss);
    int wid = tid >> 6, lane = tid & 63;
    if (lane == 0) { r1[wid] = a; r2[wid] = b; }
    __syncthreads();
    if (tid == 0) {
        psum[((size_t)ih * 8 + ck) * 2]     = r1[0] + r1[1] + r1[2] + r1[3];
        psum[((size_t)ih * 8 + ck) * 2 + 1] = r2[0] + r2[1] + r2[2] + r2[3];
    }
}

__global__ __launch_bounds__(256) void k3_final(
        const float* __restrict__ psum, const float* __restrict__ bng,
        float* __restrict__ statm, float* __restrict__ stats_) {
    int ih = blockIdx.x * 256 + threadIdx.x;
    if (ih >= 400) return;
    float S = 0.f, Q = 0.f;
    for (int ck = 0; ck < 8; ++ck) {
        S += psum[((size_t)ih * 8 + ck) * 2];
        Q += psum[((size_t)ih * 8 + ck) * 2 + 1];
    }
    int i = ih >> 3;
    float cnt = 1024.f * (float)(50 - i);
    float m = S / cnt;
    float var = Q / cnt - m * m; if (var < 0.f) var = 0.f;
    statm[ih] = m;
    stats_[ih] = bng[ih] / sqrtf(var + EPSF);
}

// K4: BN + LIF over t + max-pool over j -> poolsum [B,400]
__global__ __launch_bounds__(512) void k4_bn_lif_pool(
        const float* __restrict__ y, const float* __restrict__ statm,
        const float* __restrict__ stats_, const float* __restrict__ bnb,
        float* __restrict__ ps) {
    int b = blockIdx.x, i = blockIdx.y, J = L_ - i;
    int h = threadIdx.x >> 6, lane = threadIdx.x & 63;
    int ih = i * NH + h;
    float m = statm[ih], sc = stats_[ih], bb = bnb[ih];
    size_t yb = yoff(i);
    bool valid = lane < J;
    float v = 0.f; int cnt = 0;
    #pragma unroll
    for (int t = 0; t < T_; ++t) {
        int tb = t * B_ + b;
        float yn;
        if (valid) {
            float raw = y[yb + ((size_t)tb * NH + h) * J + lane];
            yn = (raw - m) * sc + bb;
        } else yn = -1e30f;
        v += (yn - v) * 0.5f;
        bool sp = (v >= 1.f);
        if (sp) v = 0.f;
        if (__any(sp)) cnt++;
    }
    if (lane == 0) ps[(size_t)b * 400 + ih] = (float)cnt;
}

// K5: per-b fused heads
__global__ __launch_bounds__(128) void k5_final(
        const float* __restrict__ smean, const float* __restrict__ ps,
        const float* __restrict__ convv, const float* __restrict__ fchw,
        const float* __restrict__ fchb, const float* __restrict__ fcvw,
        const float* __restrict__ fcvb, float* __restrict__ out) {
    __shared__ float sm_l[L_ * D_];
    __shared__ float vm[NV * D_];
    __shared__ float ps_l[400];
    int b = blockIdx.x, tid = threadIdx.x;
    for (int idx = tid; idx < L_ * D_; idx += 128) sm_l[idx] = smean[(size_t)b * (L_ * D_) + idx];
    for (int idx = tid; idx < 400; idx += 128) ps_l[idx] = ps[(size_t)b * 400 + idx];
    __syncthreads();
    int d = tid;
    #pragma unroll
    for (int c = 0; c < NV; ++c) {
        float a = 0.f;
        for (int l = 0; l < L_; ++l) a += convv[c * L_ + l] * sm_l[l * D_ + d];
        vm[c * D_ + d] = a;
    }
    __syncthreads();
    float acc = fchb[d] + fcvb[d];
    float ah = 0.f;
    for (int ih = 0; ih < 400; ++ih) ah += ps_l[ih] * fchw[d * 400 + ih];
    acc += ah * 0.25f;
    float av = 0.f;
    for (int cd = 0; cd < NV * D_; ++cd) av += vm[cd] * fcvw[d * (NV * D_) + cd];
    acc += av;
    out[(size_t)b * D_ + d] = acc;
}

extern "C" void kernel_launch(void* const* d_in, const int* in_sizes, int n_in,
                              void* d_out, int out_size, void* d_ws, size_t ws_size,
                              hipStream_t stream) {
    const int*   item  = (const int*)d_in[0];
    const float* tab   = (const float*)d_in[1];
    const float* lng   = (const float*)d_in[2];
    const float* lnb   = (const float*)d_in[3];
    const float* convv = (const float*)d_in[4];
    const float* convh = (const float*)d_in[5];
    const float* bng   = (const float*)d_in[6];
    const float* bnb   = (const float*)d_in[7];
    const float* fchw  = (const float*)d_in[8];
    const float* fchb  = (const float*)d_in[9];
    const float* fcvw  = (const float*)d_in[10];
    const float* fcvb  = (const float*)d_in[11];
    float* out = (float*)d_out;

    char* ws = (char*)d_ws;
    // layout (bytes):
    // s16    @ 0          13,107,200   fp16 spikes, pre-swizzled granules
    // smean  @ 13107200    6,553,600
    // y      @ 19660800   41,779,200
    // whl    @ 61440000   10,649,600   fp16 hi/lo weights [52][50][16][128], zero-padded
    // statm  @ 72089600        1,600
    // stats_ @ 72091200        1,600
    // ps     @ 72092800      409,600
    // psum   @ 72502400       25,600   -> total 72,528,000
    _Float16* s16  = (_Float16*)(ws);
    float* smean   = (float*)(ws + 13107200LL);
    float* y       = (float*)(ws + 19660800LL);
    _Float16* whl  = (_Float16*)(ws + 61440000LL);
    float* statm   = (float*)(ws + 72089600LL);
    float* stats_  = (float*)(ws + 72091200LL);
    float* ps      = (float*)(ws + 72092800LL);
    float* psum    = (float*)(ws + 72502400LL);

    hipFuncSetAttribute(reinterpret_cast<const void*>(&k2u<3>),
        hipFuncAttributeMaxDynamicSharedMemorySize, 118784);
    hipFuncSetAttribute(reinterpret_cast<const void*>(&k2u<2>),
        hipFuncAttributeMaxDynamicSharedMemorySize, 118784);
    hipFuncSetAttribute(reinterpret_cast<const void*>(&k2t),
        hipFuncAttributeMaxDynamicSharedMemorySize, 118784);

    k0_wsplit<<<dim3(50, 52), 256, 0, stream>>>(convh, whl);
    k1_embed_ln_lif<<<B_ * L_, 128, 0, stream>>>(item, tab, lng, lnb, s16, smean);
    // LPT-ordered k2 dispatches (longest kmax at y=0):
    k2u<3><<<dim3(128, 4), 512, 118784, stream>>>(s16, whl, y, 1, 0);  // g4,g3,g2,g1 (scales 4-19)
    k2u<2><<<dim3(128, 6), 512, 118784, stream>>>(s16, whl, y, 0, 2);  // g8,g7,g6,g5 + g0 j-split
    k2t<<<dim3(128, 4), 512, 118784, stream>>>(s16, whl, y);           // i0 48,44,40,36
    k3_partial<<<dim3(400, 8), 256, 0, stream>>>(y, psum);
    k3_final<<<dim3(2, 1), 256, 0, stream>>>(psum, bng, statm, stats_);
    k4_bn_lif_pool<<<dim3(B_, L_), 512, 0, stream>>>(y, statm, stats_, bnb, ps);
    k5_final<<<B_, 128, 0, stream>>>(smean, ps, convv, fchw, fchb, fcvw, fcvb, out);
}